// Round 6
// baseline (452.213 us; speedup 1.0000x reference)
//
#include <hip/hip_runtime.h>

// 3-layer GCN + mean pool. bf16 storage / MFMA GEMM / fp32 accumulate.
// R6: R4 aggregation (coalesced 16-lane/node gather, 2-way unroll, packed
// (col,w) edges) + slim GEMM: A-only LDS (17.4 KB), B-fragments streamed
// directly from global WT (32 KB, L1-resident) — no W staging, no conflicts.

#define DIN 30
#define HD  128

typedef __attribute__((ext_vector_type(8))) short v8s;
typedef __attribute__((ext_vector_type(4))) float v4f;

static __device__ __forceinline__ unsigned short f2bf(float f) {
  unsigned int u = __float_as_uint(f);
  u += 0x7fffu + ((u >> 16) & 1u);   // RNE
  return (unsigned short)(u >> 16);
}
static __device__ __forceinline__ float bf2f(unsigned short s) {
  return __uint_as_float(((unsigned int)s) << 16);
}
static __device__ __forceinline__ float bflo(unsigned int u) {
  return __uint_as_float(u << 16);
}
static __device__ __forceinline__ float bfhi(unsigned int u) {
  return __uint_as_float(u & 0xffff0000u);
}

// ---------------- preprocessing ----------------
__global__ void k_degree(const int* __restrict__ dst, int* __restrict__ deg, int E) {
  int e = blockIdx.x * blockDim.x + threadIdx.x;
  if (e < E) atomicAdd(&deg[dst[e]], 1);
}

__global__ void k_dinv(const int* __restrict__ deg, float* __restrict__ dinv, int N) {
  int i = blockIdx.x * blockDim.x + threadIdx.x;
  if (i < N) dinv[i] = rsqrtf((float)(1 + deg[i]));
}

__global__ void k_scan1(const int* __restrict__ deg, int* __restrict__ bsum, int N) {
  __shared__ int s[256];
  int tid = threadIdx.x;
  int base = blockIdx.x * 1024 + tid * 4;
  int t = 0;
#pragma unroll
  for (int j = 0; j < 4; ++j) { int idx = base + j; if (idx < N) t += deg[idx]; }
  s[tid] = t; __syncthreads();
  for (int d = 128; d > 0; d >>= 1) { if (tid < d) s[tid] += s[tid + d]; __syncthreads(); }
  if (tid == 0) bsum[blockIdx.x] = s[0];
}

__global__ void k_scan2(const int* __restrict__ bsum, int* __restrict__ boff, int nb) {
  __shared__ int s[256];
  int tid = threadIdx.x;
  int v = (tid < nb) ? bsum[tid] : 0;
  s[tid] = v; __syncthreads();
  for (int d = 1; d < 256; d <<= 1) {
    int t = (tid >= d) ? s[tid - d] : 0;
    __syncthreads();
    s[tid] += t;
    __syncthreads();
  }
  boff[tid] = s[tid] - v;
}

__global__ void k_scan3(const int* __restrict__ deg, const int* __restrict__ boff,
                        int* __restrict__ rowptr, int* __restrict__ cursor, int N) {
  __shared__ int s[256];
  int tid = threadIdx.x;
  int base = blockIdx.x * 1024 + tid * 4;
  int v[4]; int t = 0;
#pragma unroll
  for (int j = 0; j < 4; ++j) { int idx = base + j; v[j] = (idx < N) ? deg[idx] : 0; t += v[j]; }
  s[tid] = t; __syncthreads();
  for (int d = 1; d < 256; d <<= 1) {
    int u = (tid >= d) ? s[tid - d] : 0;
    __syncthreads();
    s[tid] += u;
    __syncthreads();
  }
  int run = boff[blockIdx.x] + s[tid] - t;
#pragma unroll
  for (int j = 0; j < 4; ++j) {
    int idx = base + j;
    if (idx < N) { rowptr[idx] = run; cursor[idx] = run; }
    run += v[j];
    if (idx == N - 1) rowptr[N] = run;
  }
}

// CSR scatter with fused per-edge weight: ecw[pos] = (src, dinv[src]*dinv[dst])
__global__ void k_scatter(const int* __restrict__ src, const int* __restrict__ dst,
                          const float* __restrict__ dinv,
                          int* __restrict__ cursor, uint2* __restrict__ ecw, int E) {
  int e = blockIdx.x * blockDim.x + threadIdx.x;
  if (e < E) {
    int s = src[e], d = dst[e];
    int pos = atomicAdd(&cursor[d], 1);
    float w = dinv[s] * dinv[d];
    ecw[pos] = make_uint2((unsigned int)s, __float_as_uint(w));
  }
}

// W [K][128] fp32 -> WT [128][Kstore] bf16 (zero-pad k >= Kreal)
__global__ void k_wt(const float* __restrict__ W, unsigned short* __restrict__ WT,
                     int Kreal, int Kstore) {
  int n = blockIdx.x;
  for (int k = threadIdx.x; k < Kstore; k += blockDim.x)
    WT[n * Kstore + k] = (k < Kreal) ? f2bf(W[k * 128 + n]) : (unsigned short)0;
}

// ---------------- aggregation ----------------
// L1: 30-dim fp32 input -> bf16 [N][32]. 16 lanes/node (float2/lane), 16 nodes/block.
__global__ void k_agg30(const float* __restrict__ x, const float* __restrict__ dinv,
                        const int* __restrict__ rowptr, const uint2* __restrict__ ecw,
                        unsigned short* __restrict__ out, int N) {
  int node = blockIdx.x * 16 + (threadIdx.x >> 4);
  if (node >= N) return;
  int l16 = threadIdx.x & 15;
  int f = l16 * 2;
  bool valid = (f < DIN);
  float di = dinv[node];
  float ws = di * di;
  float a0 = 0.f, a1 = 0.f;
  if (valid) {
    float2 v = *(const float2*)(x + (size_t)node * DIN + f);
    a0 = v.x * ws; a1 = v.y * ws;
  }
  int e0 = rowptr[node], e1 = rowptr[node + 1];
  int e = e0;
  for (; e + 2 <= e1; e += 2) {
    uint2 p0 = ecw[e], p1 = ecw[e + 1];
    float w0 = __uint_as_float(p0.y), w1 = __uint_as_float(p1.y);
    if (valid) {
      float2 v0 = *(const float2*)(x + (size_t)p0.x * DIN + f);
      float2 v1 = *(const float2*)(x + (size_t)p1.x * DIN + f);
      a0 = fmaf(v0.x, w0, a0); a1 = fmaf(v0.y, w0, a1);
      a0 = fmaf(v1.x, w1, a0); a1 = fmaf(v1.y, w1, a1);
    }
  }
  if (e < e1) {
    uint2 p0 = ecw[e];
    float w0 = __uint_as_float(p0.y);
    if (valid) {
      float2 v0 = *(const float2*)(x + (size_t)p0.x * DIN + f);
      a0 = fmaf(v0.x, w0, a0); a1 = fmaf(v0.y, w0, a1);
    }
  }
  unsigned int o = (unsigned int)f2bf(a0) | ((unsigned int)f2bf(a1) << 16);
  ((unsigned int*)out)[(size_t)node * 16 + l16] = o;
}

// L2/L3: 128-dim bf16 in/out. 16 lanes/node (uint4 = 8 bf16/lane), 16 nodes/block,
// 2-way edge unroll -> up to 8 independent gathers in flight per wave.
__global__ void k_agg128(const unsigned short* __restrict__ h, const float* __restrict__ dinv,
                         const int* __restrict__ rowptr, const uint2* __restrict__ ecw,
                         unsigned short* __restrict__ out, int N) {
  int node = blockIdx.x * 16 + (threadIdx.x >> 4);
  if (node >= N) return;
  int l16 = threadIdx.x & 15;
  const uint4* hp = (const uint4*)h;
  float di = dinv[node];
  float ws = di * di;
  uint4 u = hp[(size_t)node * 16 + l16];
  float a0 = bflo(u.x) * ws, a1 = bfhi(u.x) * ws;
  float a2 = bflo(u.y) * ws, a3 = bfhi(u.y) * ws;
  float a4 = bflo(u.z) * ws, a5 = bfhi(u.z) * ws;
  float a6 = bflo(u.w) * ws, a7 = bfhi(u.w) * ws;
  int e0 = rowptr[node], e1 = rowptr[node + 1];
  int e = e0;
  for (; e + 2 <= e1; e += 2) {
    uint2 p0 = ecw[e], p1 = ecw[e + 1];
    uint4 v0 = hp[(size_t)p0.x * 16 + l16];
    uint4 v1 = hp[(size_t)p1.x * 16 + l16];
    float w0 = __uint_as_float(p0.y), w1 = __uint_as_float(p1.y);
    a0 = fmaf(bflo(v0.x), w0, a0); a1 = fmaf(bfhi(v0.x), w0, a1);
    a2 = fmaf(bflo(v0.y), w0, a2); a3 = fmaf(bfhi(v0.y), w0, a3);
    a4 = fmaf(bflo(v0.z), w0, a4); a5 = fmaf(bfhi(v0.z), w0, a5);
    a6 = fmaf(bflo(v0.w), w0, a6); a7 = fmaf(bfhi(v0.w), w0, a7);
    a0 = fmaf(bflo(v1.x), w1, a0); a1 = fmaf(bfhi(v1.x), w1, a1);
    a2 = fmaf(bflo(v1.y), w1, a2); a3 = fmaf(bfhi(v1.y), w1, a3);
    a4 = fmaf(bflo(v1.z), w1, a4); a5 = fmaf(bfhi(v1.z), w1, a5);
    a6 = fmaf(bflo(v1.w), w1, a6); a7 = fmaf(bfhi(v1.w), w1, a7);
  }
  if (e < e1) {
    uint2 p0 = ecw[e];
    uint4 v0 = hp[(size_t)p0.x * 16 + l16];
    float w0 = __uint_as_float(p0.y);
    a0 = fmaf(bflo(v0.x), w0, a0); a1 = fmaf(bfhi(v0.x), w0, a1);
    a2 = fmaf(bflo(v0.y), w0, a2); a3 = fmaf(bfhi(v0.y), w0, a3);
    a4 = fmaf(bflo(v0.z), w0, a4); a5 = fmaf(bfhi(v0.z), w0, a5);
    a6 = fmaf(bflo(v0.w), w0, a6); a7 = fmaf(bfhi(v0.w), w0, a7);
  }
  uint4 o;
  o.x = (unsigned int)f2bf(a0) | ((unsigned int)f2bf(a1) << 16);
  o.y = (unsigned int)f2bf(a2) | ((unsigned int)f2bf(a3) << 16);
  o.z = (unsigned int)f2bf(a4) | ((unsigned int)f2bf(a5) << 16);
  o.w = (unsigned int)f2bf(a6) | ((unsigned int)f2bf(a7) << 16);
  ((uint4*)out)[(size_t)node * 16 + l16] = o;
}

// ---------------- MFMA GEMM: C = relu(A @ WT^T + b), bf16 ----------------
// A-only LDS (64 rows, padded). B-fragments direct from global WT (L1-resident).
template <int K>
__global__ __launch_bounds__(256) void k_gemm_mfma(const unsigned short* __restrict__ A,
                                                   const unsigned short* __restrict__ WT,
                                                   const float* __restrict__ b,
                                                   unsigned short* __restrict__ C, int N) {
  constexpr int KP = (K == 128) ? 136 : 40;
  __shared__ unsigned short As[64][KP];
  int tid = threadIdx.x;
  int rowBase = blockIdx.x * 64;

  constexpr int SEGS = K / 8;        // 16B segments per row
  constexpr int RA = 256 / SEGS;     // rows staged per iteration
  int r = tid / SEGS, seg = tid % SEGS;
#pragma unroll
  for (int it = 0; it < 64 / RA; ++it) {
    int row = it * RA + r;
    uint4 v = make_uint4(0u, 0u, 0u, 0u);
    if (rowBase + row < N) v = *(const uint4*)(A + (size_t)(rowBase + row) * K + seg * 8);
    *(uint4*)&As[row][seg * 8] = v;
  }
  __syncthreads();

  int wv = tid >> 6, lane = tid & 63, quad = lane >> 4, l15 = lane & 15;
  v8s afrag[K / 32];
#pragma unroll
  for (int kk = 0; kk < K / 32; ++kk)
    afrag[kk] = *(const v8s*)&As[wv * 16 + l15][kk * 32 + quad * 8];

#pragma unroll
  for (int t = 0; t < 8; ++t) {
    v4f acc = {0.f, 0.f, 0.f, 0.f};
#pragma unroll
    for (int kk = 0; kk < K / 32; ++kk) {
      v8s bfrag = *(const v8s*)(WT + (size_t)(t * 16 + l15) * K + kk * 32 + quad * 8);
      acc = __builtin_amdgcn_mfma_f32_16x16x32_bf16(afrag[kk], bfrag, acc, 0, 0, 0);
    }
    float bias = b[t * 16 + l15];
#pragma unroll
    for (int i = 0; i < 4; ++i) {
      int node = rowBase + wv * 16 + quad * 4 + i;
      if (node < N) {
        float o = fmaxf(acc[i] + bias, 0.f);
        C[(size_t)node * 128 + t * 16 + l15] = f2bf(o);
      }
    }
  }
}

// ---------------- mean pool over sorted batch_idx ----------------
__global__ void k_pool(const unsigned short* __restrict__ h, const int* __restrict__ batch,
                       float* __restrict__ out, int N, int G) {
  int g = blockIdx.x;
  int tid = threadIdx.x;
  int lo = 0, hi = N;
  while (lo < hi) { int mid = (lo + hi) >> 1; if (batch[mid] < g) lo = mid + 1; else hi = mid; }
  int s = lo;
  hi = N;
  while (lo < hi) { int mid = (lo + hi) >> 1; if (batch[mid] < g + 1) lo = mid + 1; else hi = mid; }
  int e = lo;
  float acc = 0.f;
  for (int n = s; n < e; ++n) acc += bf2f(h[(size_t)n * 128 + tid]);
  float cnt = (float)(e - s);
  out[(size_t)g * 128 + tid] = acc / fmaxf(cnt, 1.f);
}

extern "C" void kernel_launch(void* const* d_in, const int* in_sizes, int n_in,
                              void* d_out, int out_size, void* d_ws, size_t ws_size,
                              hipStream_t stream) {
  const float* x  = (const float*)d_in[0];
  const int* ei   = (const int*)d_in[1];
  const int* batch = (const int*)d_in[2];
  const float* W1 = (const float*)d_in[3];
  const float* b1 = (const float*)d_in[4];
  const float* W2 = (const float*)d_in[5];
  const float* b2 = (const float*)d_in[6];
  const float* W3 = (const float*)d_in[7];
  const float* b3 = (const float*)d_in[8];
  float* out = (float*)d_out;
  int N = in_sizes[2];
  int E = in_sizes[1] / 2;
  int G = out_size / HD;
  const int* src = ei;
  const int* dst = ei + E;

  size_t off = 0;
  char* ws = (char*)d_ws;
  auto alloc = [&](size_t bytes) -> void* {
    void* p = ws + off;
    off += (bytes + 255) & ~(size_t)255;
    return p;
  };
  int*   deg    = (int*)alloc((size_t)N * 4);
  float* dinv   = (float*)alloc((size_t)N * 4);
  int*   rowptr = (int*)alloc((size_t)(N + 1) * 4);
  int*   cursor = (int*)alloc((size_t)N * 4);
  uint2* ecw    = (uint2*)alloc((size_t)E * 8);
  int*   bsum   = (int*)alloc(256 * 4);
  int*   boff   = (int*)alloc(256 * 4);
  unsigned short* xagg = (unsigned short*)alloc((size_t)N * 32 * 2);
  unsigned short* hA   = (unsigned short*)alloc((size_t)N * HD * 2);
  unsigned short* hB   = (unsigned short*)alloc((size_t)N * HD * 2);
  unsigned short* W1T  = (unsigned short*)alloc(128 * 32 * 2);
  unsigned short* W2T  = (unsigned short*)alloc(128 * 128 * 2);
  unsigned short* W3T  = (unsigned short*)alloc(128 * 128 * 2);
  (void)ws_size; (void)n_in;

  int nb1024 = (N + 1023) / 1024;
  hipMemsetAsync(deg, 0, (size_t)N * 4, stream);
  k_degree<<<(E + 255) / 256, 256, 0, stream>>>(dst, deg, E);
  k_dinv<<<(N + 255) / 256, 256, 0, stream>>>(deg, dinv, N);
  k_scan1<<<nb1024, 256, 0, stream>>>(deg, bsum, N);
  k_scan2<<<1, 256, 0, stream>>>(bsum, boff, nb1024);
  k_scan3<<<nb1024, 256, 0, stream>>>(deg, boff, rowptr, cursor, N);
  k_scatter<<<(E + 255) / 256, 256, 0, stream>>>(src, dst, dinv, cursor, ecw, E);
  k_wt<<<128, 128, 0, stream>>>(W1, W1T, DIN, 32);
  k_wt<<<128, 128, 0, stream>>>(W2, W2T, 128, 128);
  k_wt<<<128, 128, 0, stream>>>(W3, W3T, 128, 128);

  int gemmBlocks = (N + 63) / 64;
  int aggBlocks = (N + 15) / 16;
  // layer 1
  k_agg30<<<aggBlocks, 256, 0, stream>>>(x, dinv, rowptr, ecw, xagg, N);
  k_gemm_mfma<32><<<gemmBlocks, 256, 0, stream>>>(xagg, W1T, b1, hA, N);
  // layer 2
  k_agg128<<<aggBlocks, 256, 0, stream>>>(hA, dinv, rowptr, ecw, hB, N);
  k_gemm_mfma<128><<<gemmBlocks, 256, 0, stream>>>(hB, W2T, b2, hA, N);
  // layer 3
  k_agg128<<<aggBlocks, 256, 0, stream>>>(hA, dinv, rowptr, ecw, hB, N);
  k_gemm_mfma<128><<<gemmBlocks, 256, 0, stream>>>(hB, W3T, b3, hA, N);
  // pool
  k_pool<<<G, 128, 0, stream>>>(hA, batch, out, N, G);
}

// Round 7
// 359.905 us; speedup vs baseline: 1.2565x; 1.2565x over previous
//
#include <hip/hip_runtime.h>

// 3-layer GCN + mean pool. bf16 storage / MFMA GEMM / fp32 accumulate.
// R7: GEMM with all-contiguous accesses:
//   - B-fragments: fragment-major WTF in global (1KB contiguous per load, L1-hot)
//   - A-fragments: direct global loads (16 rows x 64B contiguous segments)
//   - C: per-wave LDS transpose -> coalesced uint2 row-major stores
//   - no A/B LDS staging, no __syncthreads in GEMM
// Aggregation unchanged from R4 (coalesced 16-lane/node gather, 2-way unroll).

#define DIN 30
#define HD  128

typedef __attribute__((ext_vector_type(8))) short v8s;
typedef __attribute__((ext_vector_type(4))) float v4f;

static __device__ __forceinline__ unsigned short f2bf(float f) {
  unsigned int u = __float_as_uint(f);
  u += 0x7fffu + ((u >> 16) & 1u);   // RNE
  return (unsigned short)(u >> 16);
}
static __device__ __forceinline__ float bf2f(unsigned short s) {
  return __uint_as_float(((unsigned int)s) << 16);
}
static __device__ __forceinline__ float bflo(unsigned int u) {
  return __uint_as_float(u << 16);
}
static __device__ __forceinline__ float bfhi(unsigned int u) {
  return __uint_as_float(u & 0xffff0000u);
}

// ---------------- preprocessing ----------------
__global__ void k_degree(const int* __restrict__ dst, int* __restrict__ deg, int E) {
  int e = blockIdx.x * blockDim.x + threadIdx.x;
  if (e < E) atomicAdd(&deg[dst[e]], 1);
}

__global__ void k_dinv(const int* __restrict__ deg, float* __restrict__ dinv, int N) {
  int i = blockIdx.x * blockDim.x + threadIdx.x;
  if (i < N) dinv[i] = rsqrtf((float)(1 + deg[i]));
}

__global__ void k_scan1(const int* __restrict__ deg, int* __restrict__ bsum, int N) {
  __shared__ int s[256];
  int tid = threadIdx.x;
  int base = blockIdx.x * 1024 + tid * 4;
  int t = 0;
#pragma unroll
  for (int j = 0; j < 4; ++j) { int idx = base + j; if (idx < N) t += deg[idx]; }
  s[tid] = t; __syncthreads();
  for (int d = 128; d > 0; d >>= 1) { if (tid < d) s[tid] += s[tid + d]; __syncthreads(); }
  if (tid == 0) bsum[blockIdx.x] = s[0];
}

__global__ void k_scan2(const int* __restrict__ bsum, int* __restrict__ boff, int nb) {
  __shared__ int s[256];
  int tid = threadIdx.x;
  int v = (tid < nb) ? bsum[tid] : 0;
  s[tid] = v; __syncthreads();
  for (int d = 1; d < 256; d <<= 1) {
    int t = (tid >= d) ? s[tid - d] : 0;
    __syncthreads();
    s[tid] += t;
    __syncthreads();
  }
  boff[tid] = s[tid] - v;
}

__global__ void k_scan3(const int* __restrict__ deg, const int* __restrict__ boff,
                        int* __restrict__ rowptr, int* __restrict__ cursor, int N) {
  __shared__ int s[256];
  int tid = threadIdx.x;
  int base = blockIdx.x * 1024 + tid * 4;
  int v[4]; int t = 0;
#pragma unroll
  for (int j = 0; j < 4; ++j) { int idx = base + j; v[j] = (idx < N) ? deg[idx] : 0; t += v[j]; }
  s[tid] = t; __syncthreads();
  for (int d = 1; d < 256; d <<= 1) {
    int u = (tid >= d) ? s[tid - d] : 0;
    __syncthreads();
    s[tid] += u;
    __syncthreads();
  }
  int run = boff[blockIdx.x] + s[tid] - t;
#pragma unroll
  for (int j = 0; j < 4; ++j) {
    int idx = base + j;
    if (idx < N) { rowptr[idx] = run; cursor[idx] = run; }
    run += v[j];
    if (idx == N - 1) rowptr[N] = run;
  }
}

// CSR scatter with fused per-edge weight: ecw[pos] = (src, dinv[src]*dinv[dst])
__global__ void k_scatter(const int* __restrict__ src, const int* __restrict__ dst,
                          const float* __restrict__ dinv,
                          int* __restrict__ cursor, uint2* __restrict__ ecw, int E) {
  int e = blockIdx.x * blockDim.x + threadIdx.x;
  if (e < E) {
    int s = src[e], d = dst[e];
    int pos = atomicAdd(&cursor[d], 1);
    float w = dinv[s] * dinv[d];
    ecw[pos] = make_uint2((unsigned int)s, __float_as_uint(w));
  }
}

// W [K][128] fp32 -> fragment-major WTF bf16:
// element idx = chunk*8 + j, chunk c = ((t*KK+kk)*4+quad)*16+l15,
// holds B[k=kk*32+quad*8+j][n=t*16+l15]  (zero for k >= Kreal)
__global__ void k_wtf(const float* __restrict__ W, unsigned short* __restrict__ WTF,
                      int Kreal, int KK) {
  int idx = blockIdx.x * blockDim.x + threadIdx.x;
  int total = 8 * KK * 64 * 8;
  if (idx >= total) return;
  int j = idx & 7;
  int c = idx >> 3;
  int l15 = c & 15;
  int quad = (c >> 4) & 3;
  int kk = (c >> 6) % KK;
  int t = c / (64 * KK);
  int k = kk * 32 + quad * 8 + j;
  int n = t * 16 + l15;
  WTF[idx] = (k < Kreal) ? f2bf(W[k * 128 + n]) : (unsigned short)0;
}

// ---------------- aggregation (R4) ----------------
__global__ void k_agg30(const float* __restrict__ x, const float* __restrict__ dinv,
                        const int* __restrict__ rowptr, const uint2* __restrict__ ecw,
                        unsigned short* __restrict__ out, int N) {
  int node = blockIdx.x * 16 + (threadIdx.x >> 4);
  if (node >= N) return;
  int l16 = threadIdx.x & 15;
  int f = l16 * 2;
  bool valid = (f < DIN);
  float di = dinv[node];
  float ws = di * di;
  float a0 = 0.f, a1 = 0.f;
  if (valid) {
    float2 v = *(const float2*)(x + (size_t)node * DIN + f);
    a0 = v.x * ws; a1 = v.y * ws;
  }
  int e0 = rowptr[node], e1 = rowptr[node + 1];
  int e = e0;
  for (; e + 2 <= e1; e += 2) {
    uint2 p0 = ecw[e], p1 = ecw[e + 1];
    float w0 = __uint_as_float(p0.y), w1 = __uint_as_float(p1.y);
    if (valid) {
      float2 v0 = *(const float2*)(x + (size_t)p0.x * DIN + f);
      float2 v1 = *(const float2*)(x + (size_t)p1.x * DIN + f);
      a0 = fmaf(v0.x, w0, a0); a1 = fmaf(v0.y, w0, a1);
      a0 = fmaf(v1.x, w1, a0); a1 = fmaf(v1.y, w1, a1);
    }
  }
  if (e < e1) {
    uint2 p0 = ecw[e];
    float w0 = __uint_as_float(p0.y);
    if (valid) {
      float2 v0 = *(const float2*)(x + (size_t)p0.x * DIN + f);
      a0 = fmaf(v0.x, w0, a0); a1 = fmaf(v0.y, w0, a1);
    }
  }
  unsigned int o = (unsigned int)f2bf(a0) | ((unsigned int)f2bf(a1) << 16);
  ((unsigned int*)out)[(size_t)node * 16 + l16] = o;
}

__global__ void k_agg128(const unsigned short* __restrict__ h, const float* __restrict__ dinv,
                         const int* __restrict__ rowptr, const uint2* __restrict__ ecw,
                         unsigned short* __restrict__ out, int N) {
  int node = blockIdx.x * 16 + (threadIdx.x >> 4);
  if (node >= N) return;
  int l16 = threadIdx.x & 15;
  const uint4* hp = (const uint4*)h;
  float di = dinv[node];
  float ws = di * di;
  uint4 u = hp[(size_t)node * 16 + l16];
  float a0 = bflo(u.x) * ws, a1 = bfhi(u.x) * ws;
  float a2 = bflo(u.y) * ws, a3 = bfhi(u.y) * ws;
  float a4 = bflo(u.z) * ws, a5 = bfhi(u.z) * ws;
  float a6 = bflo(u.w) * ws, a7 = bfhi(u.w) * ws;
  int e0 = rowptr[node], e1 = rowptr[node + 1];
  int e = e0;
  for (; e + 2 <= e1; e += 2) {
    uint2 p0 = ecw[e], p1 = ecw[e + 1];
    uint4 v0 = hp[(size_t)p0.x * 16 + l16];
    uint4 v1 = hp[(size_t)p1.x * 16 + l16];
    float w0 = __uint_as_float(p0.y), w1 = __uint_as_float(p1.y);
    a0 = fmaf(bflo(v0.x), w0, a0); a1 = fmaf(bfhi(v0.x), w0, a1);
    a2 = fmaf(bflo(v0.y), w0, a2); a3 = fmaf(bfhi(v0.y), w0, a3);
    a4 = fmaf(bflo(v0.z), w0, a4); a5 = fmaf(bfhi(v0.z), w0, a5);
    a6 = fmaf(bflo(v0.w), w0, a6); a7 = fmaf(bfhi(v0.w), w0, a7);
    a0 = fmaf(bflo(v1.x), w1, a0); a1 = fmaf(bfhi(v1.x), w1, a1);
    a2 = fmaf(bflo(v1.y), w1, a2); a3 = fmaf(bfhi(v1.y), w1, a3);
    a4 = fmaf(bflo(v1.z), w1, a4); a5 = fmaf(bfhi(v1.z), w1, a5);
    a6 = fmaf(bflo(v1.w), w1, a6); a7 = fmaf(bfhi(v1.w), w1, a7);
  }
  if (e < e1) {
    uint2 p0 = ecw[e];
    uint4 v0 = hp[(size_t)p0.x * 16 + l16];
    float w0 = __uint_as_float(p0.y);
    a0 = fmaf(bflo(v0.x), w0, a0); a1 = fmaf(bfhi(v0.x), w0, a1);
    a2 = fmaf(bflo(v0.y), w0, a2); a3 = fmaf(bfhi(v0.y), w0, a3);
    a4 = fmaf(bflo(v0.z), w0, a4); a5 = fmaf(bfhi(v0.z), w0, a5);
    a6 = fmaf(bflo(v0.w), w0, a6); a7 = fmaf(bfhi(v0.w), w0, a7);
  }
  uint4 o;
  o.x = (unsigned int)f2bf(a0) | ((unsigned int)f2bf(a1) << 16);
  o.y = (unsigned int)f2bf(a2) | ((unsigned int)f2bf(a3) << 16);
  o.z = (unsigned int)f2bf(a4) | ((unsigned int)f2bf(a5) << 16);
  o.w = (unsigned int)f2bf(a6) | ((unsigned int)f2bf(a7) << 16);
  ((uint4*)out)[(size_t)node * 16 + l16] = o;
}

// ---------------- MFMA GEMM: C = relu(A @ W + b), all-contiguous ----------------
// A [N][K] bf16 row-major (direct loads), WTF fragment-major (1KB coalesced loads),
// C [N][128] bf16 via per-wave LDS transpose. Block = 4 waves x 16 rows.
template <int K>
__global__ __launch_bounds__(256) void k_gemm_mfma(const unsigned short* __restrict__ A,
                                                   const unsigned short* __restrict__ WTF,
                                                   const float* __restrict__ b,
                                                   unsigned short* __restrict__ C, int N) {
  constexpr int KK = K / 32;
  constexpr int CP = 132;            // ushort stride: write-side conflict-free
  __shared__ unsigned short Cs[4][16 * CP];
  int tid = threadIdx.x;
  int wv = tid >> 6, lane = tid & 63, quad = lane >> 4, l15 = lane & 15;
  int row0 = blockIdx.x * 64 + wv * 16;
  int arow = row0 + l15;

  v8s af[KK];
#pragma unroll
  for (int kk = 0; kk < KK; ++kk) {
    if (arow < N) af[kk] = *(const v8s*)(A + (size_t)arow * K + kk * 32 + quad * 8);
    else          af[kk] = (v8s)(short)0;
  }

#pragma unroll
  for (int t = 0; t < 8; ++t) {
    v4f acc = {0.f, 0.f, 0.f, 0.f};
#pragma unroll
    for (int kk = 0; kk < KK; ++kk) {
      v8s bf = *(const v8s*)(WTF + (size_t)(((t * KK + kk) * 4 + quad) * 16 + l15) * 8);
      acc = __builtin_amdgcn_mfma_f32_16x16x32_bf16(af[kk], bf, acc, 0, 0, 0);
    }
    float bias = b[t * 16 + l15];
#pragma unroll
    for (int i = 0; i < 4; ++i) {
      float o = fmaxf(acc[i] + bias, 0.f);
      Cs[wv][(quad * 4 + i) * CP + t * 16 + l15] = f2bf(o);
    }
  }

  // read back row-major (uint2) and store coalesced
#pragma unroll
  for (int j = 0; j < 8; ++j) {
    int linear = j * 64 + lane;        // 16 rows x 32 uint2
    int r = linear >> 5, ch = linear & 31;
    uint2 v = *(const uint2*)&Cs[wv][r * CP + ch * 4];
    int row = row0 + r;
    if (row < N) ((uint2*)C)[(size_t)row * 32 + ch] = v;
  }
}

// ---------------- mean pool over sorted batch_idx ----------------
__global__ void k_pool(const unsigned short* __restrict__ h, const int* __restrict__ batch,
                       float* __restrict__ out, int N, int G) {
  int g = blockIdx.x;
  int tid = threadIdx.x;
  int lo = 0, hi = N;
  while (lo < hi) { int mid = (lo + hi) >> 1; if (batch[mid] < g) lo = mid + 1; else hi = mid; }
  int s = lo;
  hi = N;
  while (lo < hi) { int mid = (lo + hi) >> 1; if (batch[mid] < g + 1) lo = mid + 1; else hi = mid; }
  int e = lo;
  float acc = 0.f;
  for (int n = s; n < e; ++n) acc += bf2f(h[(size_t)n * 128 + tid]);
  float cnt = (float)(e - s);
  out[(size_t)g * 128 + tid] = acc / fmaxf(cnt, 1.f);
}

extern "C" void kernel_launch(void* const* d_in, const int* in_sizes, int n_in,
                              void* d_out, int out_size, void* d_ws, size_t ws_size,
                              hipStream_t stream) {
  const float* x  = (const float*)d_in[0];
  const int* ei   = (const int*)d_in[1];
  const int* batch = (const int*)d_in[2];
  const float* W1 = (const float*)d_in[3];
  const float* b1 = (const float*)d_in[4];
  const float* W2 = (const float*)d_in[5];
  const float* b2 = (const float*)d_in[6];
  const float* W3 = (const float*)d_in[7];
  const float* b3 = (const float*)d_in[8];
  float* out = (float*)d_out;
  int N = in_sizes[2];
  int E = in_sizes[1] / 2;
  int G = out_size / HD;
  const int* src = ei;
  const int* dst = ei + E;

  size_t off = 0;
  char* ws = (char*)d_ws;
  auto alloc = [&](size_t bytes) -> void* {
    void* p = ws + off;
    off += (bytes + 255) & ~(size_t)255;
    return p;
  };
  int*   deg    = (int*)alloc((size_t)N * 4);
  float* dinv   = (float*)alloc((size_t)N * 4);
  int*   rowptr = (int*)alloc((size_t)(N + 1) * 4);
  int*   cursor = (int*)alloc((size_t)N * 4);
  uint2* ecw    = (uint2*)alloc((size_t)E * 8);
  int*   bsum   = (int*)alloc(256 * 4);
  int*   boff   = (int*)alloc(256 * 4);
  unsigned short* xagg = (unsigned short*)alloc((size_t)N * 32 * 2);
  unsigned short* hA   = (unsigned short*)alloc((size_t)N * HD * 2);
  unsigned short* hB   = (unsigned short*)alloc((size_t)N * HD * 2);
  unsigned short* W1F  = (unsigned short*)alloc(8 * 1 * 64 * 8 * 2);
  unsigned short* W2F  = (unsigned short*)alloc(8 * 4 * 64 * 8 * 2);
  unsigned short* W3F  = (unsigned short*)alloc(8 * 4 * 64 * 8 * 2);
  (void)ws_size; (void)n_in;

  int nb1024 = (N + 1023) / 1024;
  hipMemsetAsync(deg, 0, (size_t)N * 4, stream);
  k_degree<<<(E + 255) / 256, 256, 0, stream>>>(dst, deg, E);
  k_dinv<<<(N + 255) / 256, 256, 0, stream>>>(deg, dinv, N);
  k_scan1<<<nb1024, 256, 0, stream>>>(deg, bsum, N);
  k_scan2<<<1, 256, 0, stream>>>(bsum, boff, nb1024);
  k_scan3<<<nb1024, 256, 0, stream>>>(deg, boff, rowptr, cursor, N);
  k_scatter<<<(E + 255) / 256, 256, 0, stream>>>(src, dst, dinv, cursor, ecw, E);
  k_wtf<<<16, 256, 0, stream>>>(W1, W1F, DIN, 1);
  k_wtf<<<64, 256, 0, stream>>>(W2, W2F, 128, 4);
  k_wtf<<<64, 256, 0, stream>>>(W3, W3F, 128, 4);

  int gemmBlocks = (N + 63) / 64;
  int aggBlocks = (N + 15) / 16;
  // layer 1
  k_agg30<<<aggBlocks, 256, 0, stream>>>(x, dinv, rowptr, ecw, xagg, N);
  k_gemm_mfma<32><<<gemmBlocks, 256, 0, stream>>>(xagg, W1F, b1, hA, N);
  // layer 2
  k_agg128<<<aggBlocks, 256, 0, stream>>>(hA, dinv, rowptr, ecw, hB, N);
  k_gemm_mfma<128><<<gemmBlocks, 256, 0, stream>>>(hB, W2F, b2, hA, N);
  // layer 3
  k_agg128<<<aggBlocks, 256, 0, stream>>>(hA, dinv, rowptr, ecw, hB, N);
  k_gemm_mfma<128><<<gemmBlocks, 256, 0, stream>>>(hB, W3F, b3, hA, N);
  // pool
  k_pool<<<G, 128, 0, stream>>>(hA, batch, out, N, G);
}

// Round 8
// 323.053 us; speedup vs baseline: 1.3998x; 1.1141x over previous
//
#include <hip/hip_runtime.h>

// 3-layer GCN + mean pool. bf16 storage / MFMA GEMM / fp32 accumulate.
// R8: per-layer fused aggregate+GEMM:
//   phase 1: R4-style coalesced gather (16 lanes/node, uint4/lane, 2-way
//            unroll) accumulating fp32, writing bf16 rows into LDS
//   phase 2: MFMA with A-fragments from LDS (R6 path), B-fragments from
//            fragment-major global WTF (R7 path, 1KB coalesced, L1-hot)
//   phase 3: C via per-wave LDS transpose -> coalesced uint2 stores (R7)
// Pool: precomputed segment bounds (no binary search) + wave/graph reads.

#define DIN 30
#define HD  128

typedef __attribute__((ext_vector_type(8))) short v8s;
typedef __attribute__((ext_vector_type(4))) float v4f;

static __device__ __forceinline__ unsigned short f2bf(float f) {
  unsigned int u = __float_as_uint(f);
  u += 0x7fffu + ((u >> 16) & 1u);   // RNE
  return (unsigned short)(u >> 16);
}
static __device__ __forceinline__ float bflo(unsigned int u) {
  return __uint_as_float(u << 16);
}
static __device__ __forceinline__ float bfhi(unsigned int u) {
  return __uint_as_float(u & 0xffff0000u);
}

// ---------------- preprocessing ----------------
__global__ void k_degree(const int* __restrict__ dst, int* __restrict__ deg, int E) {
  int e = blockIdx.x * blockDim.x + threadIdx.x;
  if (e < E) atomicAdd(&deg[dst[e]], 1);
}

__global__ void k_dinv(const int* __restrict__ deg, float* __restrict__ dinv, int N) {
  int i = blockIdx.x * blockDim.x + threadIdx.x;
  if (i < N) dinv[i] = rsqrtf((float)(1 + deg[i]));
}

__global__ void k_scan1(const int* __restrict__ deg, int* __restrict__ bsum, int N) {
  __shared__ int s[256];
  int tid = threadIdx.x;
  int base = blockIdx.x * 1024 + tid * 4;
  int t = 0;
#pragma unroll
  for (int j = 0; j < 4; ++j) { int idx = base + j; if (idx < N) t += deg[idx]; }
  s[tid] = t; __syncthreads();
  for (int d = 128; d > 0; d >>= 1) { if (tid < d) s[tid] += s[tid + d]; __syncthreads(); }
  if (tid == 0) bsum[blockIdx.x] = s[0];
}

__global__ void k_scan2(const int* __restrict__ bsum, int* __restrict__ boff, int nb) {
  __shared__ int s[256];
  int tid = threadIdx.x;
  int v = (tid < nb) ? bsum[tid] : 0;
  s[tid] = v; __syncthreads();
  for (int d = 1; d < 256; d <<= 1) {
    int t = (tid >= d) ? s[tid - d] : 0;
    __syncthreads();
    s[tid] += t;
    __syncthreads();
  }
  boff[tid] = s[tid] - v;
}

__global__ void k_scan3(const int* __restrict__ deg, const int* __restrict__ boff,
                        int* __restrict__ rowptr, int* __restrict__ cursor, int N) {
  __shared__ int s[256];
  int tid = threadIdx.x;
  int base = blockIdx.x * 1024 + tid * 4;
  int v[4]; int t = 0;
#pragma unroll
  for (int j = 0; j < 4; ++j) { int idx = base + j; v[j] = (idx < N) ? deg[idx] : 0; t += v[j]; }
  s[tid] = t; __syncthreads();
  for (int d = 1; d < 256; d <<= 1) {
    int u = (tid >= d) ? s[tid - d] : 0;
    __syncthreads();
    s[tid] += u;
    __syncthreads();
  }
  int run = boff[blockIdx.x] + s[tid] - t;
#pragma unroll
  for (int j = 0; j < 4; ++j) {
    int idx = base + j;
    if (idx < N) { rowptr[idx] = run; cursor[idx] = run; }
    run += v[j];
    if (idx == N - 1) rowptr[N] = run;
  }
}

// CSR scatter with fused per-edge weight: ecw[pos] = (src, dinv[src]*dinv[dst])
__global__ void k_scatter(const int* __restrict__ src, const int* __restrict__ dst,
                          const float* __restrict__ dinv,
                          int* __restrict__ cursor, uint2* __restrict__ ecw, int E) {
  int e = blockIdx.x * blockDim.x + threadIdx.x;
  if (e < E) {
    int s = src[e], d = dst[e];
    int pos = atomicAdd(&cursor[d], 1);
    float w = dinv[s] * dinv[d];
    ecw[pos] = make_uint2((unsigned int)s, __float_as_uint(w));
  }
}

// W [K][128] fp32 -> fragment-major WTF bf16 (R7)
__global__ void k_wtf(const float* __restrict__ W, unsigned short* __restrict__ WTF,
                      int Kreal, int KK) {
  int idx = blockIdx.x * blockDim.x + threadIdx.x;
  int total = 8 * KK * 64 * 8;
  if (idx >= total) return;
  int j = idx & 7;
  int c = idx >> 3;
  int l15 = c & 15;
  int quad = (c >> 4) & 3;
  int kk = (c >> 6) % KK;
  int t = c / (64 * KK);
  int k = kk * 32 + quad * 8 + j;
  int n = t * 16 + l15;
  WTF[idx] = (k < Kreal) ? f2bf(W[k * 128 + n]) : (unsigned short)0;
}

// graph segment starts from sorted batch_idx
__global__ void k_bounds(const int* __restrict__ batch, int* __restrict__ gstart,
                         int N, int G) {
  int i = blockIdx.x * blockDim.x + threadIdx.x;
  if (i >= N) return;
  int b = batch[i];
  int prev = (i == 0) ? -1 : batch[i - 1];
  for (int g = prev + 1; g <= b; ++g) gstart[g] = i;
  if (i == N - 1)
    for (int g = b + 1; g <= G; ++g) gstart[g] = N;
}

// ---------------- fused aggregate + MFMA GEMM ----------------
// Block = 64 nodes, 256 threads.
// K=32: input fp32 x [N][30]; K=128: input bf16 h [N][128].
template <int K>
__global__ __launch_bounds__(256) void k_fused(const void* __restrict__ hin,
                                               const unsigned short* __restrict__ WTF,
                                               const float* __restrict__ b,
                                               const int* __restrict__ rowptr,
                                               const uint2* __restrict__ ecw,
                                               const float* __restrict__ dinv,
                                               unsigned short* __restrict__ C, int N) {
  constexpr int KK = K / 32;
  constexpr int KP = (K == 128) ? 136 : 40;   // row stride (ushorts): 272/80 B, 16B-aligned
  constexpr int CP = 132;                     // C-transpose stride
  constexpr int SMSZ = (64 * KP > 4 * 16 * CP) ? 64 * KP : 4 * 16 * CP;
  __shared__ __align__(16) unsigned short sm[SMSZ];

  int tid = threadIdx.x;
  int l16 = tid & 15;
  int row0 = blockIdx.x * 64;

  // ---- phase 1: aggregate 64 rows into LDS (bf16) ----
#pragma unroll
  for (int p = 0; p < 4; ++p) {
    int nl = p * 16 + (tid >> 4);
    int node = row0 + nl;
    if (K == 32) {
      const float* xp = (const float*)hin;
      int f = l16 * 2;
      bool valid = (node < N) && (f < DIN);
      float a0 = 0.f, a1 = 0.f;
      if (node < N) {
        float di = dinv[node];
        float wsf = di * di;
        if (valid) {
          float2 v = *(const float2*)(xp + (size_t)node * DIN + f);
          a0 = v.x * wsf; a1 = v.y * wsf;
        }
        int e0 = rowptr[node], e1 = rowptr[node + 1];
        int e = e0;
        for (; e + 2 <= e1; e += 2) {
          uint2 p0 = ecw[e], p1 = ecw[e + 1];
          float w0 = __uint_as_float(p0.y), w1 = __uint_as_float(p1.y);
          if (valid) {
            float2 v0 = *(const float2*)(xp + (size_t)p0.x * DIN + f);
            float2 v1 = *(const float2*)(xp + (size_t)p1.x * DIN + f);
            a0 = fmaf(v0.x, w0, a0); a1 = fmaf(v0.y, w0, a1);
            a0 = fmaf(v1.x, w1, a0); a1 = fmaf(v1.y, w1, a1);
          }
        }
        if (e < e1) {
          uint2 p0 = ecw[e];
          float w0 = __uint_as_float(p0.y);
          if (valid) {
            float2 v0 = *(const float2*)(xp + (size_t)p0.x * DIN + f);
            a0 = fmaf(v0.x, w0, a0); a1 = fmaf(v0.y, w0, a1);
          }
        }
      }
      *(unsigned int*)&sm[nl * KP + l16 * 2] =
          (unsigned int)f2bf(a0) | ((unsigned int)f2bf(a1) << 16);
    } else {
      const uint4* hp = (const uint4*)hin;
      float a0 = 0.f, a1 = 0.f, a2 = 0.f, a3 = 0.f, a4 = 0.f, a5 = 0.f, a6 = 0.f, a7 = 0.f;
      if (node < N) {
        float di = dinv[node];
        float wsf = di * di;
        uint4 u = hp[(size_t)node * 16 + l16];
        a0 = bflo(u.x) * wsf; a1 = bfhi(u.x) * wsf;
        a2 = bflo(u.y) * wsf; a3 = bfhi(u.y) * wsf;
        a4 = bflo(u.z) * wsf; a5 = bfhi(u.z) * wsf;
        a6 = bflo(u.w) * wsf; a7 = bfhi(u.w) * wsf;
        int e0 = rowptr[node], e1 = rowptr[node + 1];
        int e = e0;
        for (; e + 2 <= e1; e += 2) {
          uint2 p0 = ecw[e], p1 = ecw[e + 1];
          uint4 v0 = hp[(size_t)p0.x * 16 + l16];
          uint4 v1 = hp[(size_t)p1.x * 16 + l16];
          float w0 = __uint_as_float(p0.y), w1 = __uint_as_float(p1.y);
          a0 = fmaf(bflo(v0.x), w0, a0); a1 = fmaf(bfhi(v0.x), w0, a1);
          a2 = fmaf(bflo(v0.y), w0, a2); a3 = fmaf(bfhi(v0.y), w0, a3);
          a4 = fmaf(bflo(v0.z), w0, a4); a5 = fmaf(bfhi(v0.z), w0, a5);
          a6 = fmaf(bflo(v0.w), w0, a6); a7 = fmaf(bfhi(v0.w), w0, a7);
          a0 = fmaf(bflo(v1.x), w1, a0); a1 = fmaf(bfhi(v1.x), w1, a1);
          a2 = fmaf(bflo(v1.y), w1, a2); a3 = fmaf(bfhi(v1.y), w1, a3);
          a4 = fmaf(bflo(v1.z), w1, a4); a5 = fmaf(bfhi(v1.z), w1, a5);
          a6 = fmaf(bflo(v1.w), w1, a6); a7 = fmaf(bfhi(v1.w), w1, a7);
        }
        if (e < e1) {
          uint2 p0 = ecw[e];
          uint4 v0 = hp[(size_t)p0.x * 16 + l16];
          float w0 = __uint_as_float(p0.y);
          a0 = fmaf(bflo(v0.x), w0, a0); a1 = fmaf(bfhi(v0.x), w0, a1);
          a2 = fmaf(bflo(v0.y), w0, a2); a3 = fmaf(bfhi(v0.y), w0, a3);
          a4 = fmaf(bflo(v0.z), w0, a4); a5 = fmaf(bfhi(v0.z), w0, a5);
          a6 = fmaf(bflo(v0.w), w0, a6); a7 = fmaf(bfhi(v0.w), w0, a7);
        }
      }
      uint4 o;
      o.x = (unsigned int)f2bf(a0) | ((unsigned int)f2bf(a1) << 16);
      o.y = (unsigned int)f2bf(a2) | ((unsigned int)f2bf(a3) << 16);
      o.z = (unsigned int)f2bf(a4) | ((unsigned int)f2bf(a5) << 16);
      o.w = (unsigned int)f2bf(a6) | ((unsigned int)f2bf(a7) << 16);
      *(uint4*)&sm[nl * KP + l16 * 8] = o;
    }
  }
  __syncthreads();

  // ---- phase 2: A-fragments from LDS ----
  int wv = tid >> 6, lane = tid & 63, quad = lane >> 4, l15 = lane & 15;
  v8s af[KK];
#pragma unroll
  for (int kk = 0; kk < KK; ++kk)
    af[kk] = *(const v8s*)&sm[(wv * 16 + l15) * KP + kk * 32 + quad * 8];
  __syncthreads();   // before reusing sm as C-transpose buffer

  // ---- phase 3: MFMA + C transpose + coalesced store ----
#pragma unroll
  for (int t = 0; t < 8; ++t) {
    v4f acc = {0.f, 0.f, 0.f, 0.f};
#pragma unroll
    for (int kk = 0; kk < KK; ++kk) {
      v8s bf = *(const v8s*)(WTF + (size_t)(((t * KK + kk) * 4 + quad) * 16 + l15) * 8);
      acc = __builtin_amdgcn_mfma_f32_16x16x32_bf16(af[kk], bf, acc, 0, 0, 0);
    }
    float bias = b[t * 16 + l15];
#pragma unroll
    for (int i = 0; i < 4; ++i) {
      float o = fmaxf(acc[i] + bias, 0.f);
      sm[wv * 16 * CP + (quad * 4 + i) * CP + t * 16 + l15] = f2bf(o);
    }
  }
  int crow0 = row0 + wv * 16;
#pragma unroll
  for (int j = 0; j < 8; ++j) {
    int linear = j * 64 + lane;
    int r = linear >> 5, ch = linear & 31;
    uint2 v = *(const uint2*)&sm[wv * 16 * CP + r * CP + ch * 4];
    int row = crow0 + r;
    if (row < N) ((uint2*)C)[(size_t)row * 32 + ch] = v;
  }
}

// ---------------- mean pool: 1 wave/graph, precomputed bounds ----------------
__global__ void k_pool(const unsigned short* __restrict__ h, const int* __restrict__ gstart,
                       float* __restrict__ out, int G) {
  int g = blockIdx.x * 4 + (threadIdx.x >> 6);
  if (g >= G) return;
  int lane = threadIdx.x & 63;
  int s = gstart[g], e = gstart[g + 1];
  const unsigned int* hp = (const unsigned int*)h;
  float a0 = 0.f, a1 = 0.f;
  for (int n = s; n < e; ++n) {
    unsigned int u = hp[(size_t)n * 64 + lane];
    a0 += bflo(u); a1 += bfhi(u);
  }
  float inv = 1.f / fmaxf((float)(e - s), 1.f);
  ((float2*)out)[(size_t)g * 64 + lane] = make_float2(a0 * inv, a1 * inv);
}

extern "C" void kernel_launch(void* const* d_in, const int* in_sizes, int n_in,
                              void* d_out, int out_size, void* d_ws, size_t ws_size,
                              hipStream_t stream) {
  const float* x  = (const float*)d_in[0];
  const int* ei   = (const int*)d_in[1];
  const int* batch = (const int*)d_in[2];
  const float* W1 = (const float*)d_in[3];
  const float* b1 = (const float*)d_in[4];
  const float* W2 = (const float*)d_in[5];
  const float* b2 = (const float*)d_in[6];
  const float* W3 = (const float*)d_in[7];
  const float* b3 = (const float*)d_in[8];
  float* out = (float*)d_out;
  int N = in_sizes[2];
  int E = in_sizes[1] / 2;
  int G = out_size / HD;
  const int* src = ei;
  const int* dst = ei + E;

  size_t off = 0;
  char* ws = (char*)d_ws;
  auto alloc = [&](size_t bytes) -> void* {
    void* p = ws + off;
    off += (bytes + 255) & ~(size_t)255;
    return p;
  };
  int*   deg    = (int*)alloc((size_t)N * 4);
  float* dinv   = (float*)alloc((size_t)N * 4);
  int*   rowptr = (int*)alloc((size_t)(N + 1) * 4);
  int*   cursor = (int*)alloc((size_t)N * 4);
  uint2* ecw    = (uint2*)alloc((size_t)E * 8);
  int*   bsum   = (int*)alloc(256 * 4);
  int*   boff   = (int*)alloc(256 * 4);
  int*   gstart = (int*)alloc((size_t)(G + 1) * 4);
  unsigned short* hA  = (unsigned short*)alloc((size_t)N * HD * 2);
  unsigned short* hB  = (unsigned short*)alloc((size_t)N * HD * 2);
  unsigned short* W1F = (unsigned short*)alloc(8 * 1 * 64 * 8 * 2);
  unsigned short* W2F = (unsigned short*)alloc(8 * 4 * 64 * 8 * 2);
  unsigned short* W3F = (unsigned short*)alloc(8 * 4 * 64 * 8 * 2);
  (void)ws_size; (void)n_in;

  int nb1024 = (N + 1023) / 1024;
  hipMemsetAsync(deg, 0, (size_t)N * 4, stream);
  k_degree<<<(E + 255) / 256, 256, 0, stream>>>(dst, deg, E);
  k_dinv<<<(N + 255) / 256, 256, 0, stream>>>(deg, dinv, N);
  k_scan1<<<nb1024, 256, 0, stream>>>(deg, bsum, N);
  k_scan2<<<1, 256, 0, stream>>>(bsum, boff, nb1024);
  k_scan3<<<nb1024, 256, 0, stream>>>(deg, boff, rowptr, cursor, N);
  k_scatter<<<(E + 255) / 256, 256, 0, stream>>>(src, dst, dinv, cursor, ecw, E);
  k_wtf<<<16, 256, 0, stream>>>(W1, W1F, DIN, 1);
  k_wtf<<<64, 256, 0, stream>>>(W2, W2F, 128, 4);
  k_wtf<<<64, 256, 0, stream>>>(W3, W3F, 128, 4);
  k_bounds<<<(N + 255) / 256, 256, 0, stream>>>(batch, gstart, N, G);

  int fusedBlocks = (N + 63) / 64;
  k_fused<32><<<fusedBlocks, 256, 0, stream>>>(x, W1F, b1, rowptr, ecw, dinv, hA, N);
  k_fused<128><<<fusedBlocks, 256, 0, stream>>>(hA, W2F, b2, rowptr, ecw, dinv, hB, N);
  k_fused<128><<<fusedBlocks, 256, 0, stream>>>(hB, W3F, b3, rowptr, ecw, dinv, hA, N);
  k_pool<<<(G + 3) / 4, 256, 0, stream>>>(hA, gstart, out, G);
}